// Round 1
// baseline (81.538 us; speedup 1.0000x reference)
//
#include <hip/hip_runtime.h>

// Problem constants (from reference)
#define T_LEN   4096
#define BKB     256            // B_ENV * K_OPT
#define OBSD    3
#define NCHUNK  256            // time chunks
#define TC      (T_LEN / NCHUNK)   // 16 steps per chunk
#define TOT     (T_LEN * BKB)  // elements per output tensor
#define EPSF    1e-5f

// ---- fast math helpers ----
__device__ __forceinline__ float sigmoid_f(float x) {
    return __builtin_amdgcn_rcpf(1.0f + __expf(-x));
}
__device__ __forceinline__ float silu_f(float x) { return x * sigmoid_f(x); }
__device__ __forceinline__ float softplus_f(float x) {
    return x > 15.0f ? x : __logf(1.0f + __expf(x));
}

// ---- per-thread parameter block (all uniform; compiler scalarizes) ----
struct Pars {
    float Wi[6];    // W_in (2,3) row-major
    float bi[2];
    float Wp[14];   // W_inproj (7,2) row-major
    float cw0[4], cw1[4], cb[4];   // conv_w (4,2), conv_b
    float dtb;      // dt_bias[0]
    float A;        // -exp(A_log[0])
};

__device__ __forceinline__ Pars load_pars(const float* W_in, const float* b_in,
                                          const float* W_inproj, const float* conv_w,
                                          const float* conv_b, const float* dt_bias,
                                          const float* A_log) {
    Pars p;
#pragma unroll
    for (int i = 0; i < 6; ++i) p.Wi[i] = W_in[i];
    p.bi[0] = b_in[0]; p.bi[1] = b_in[1];
#pragma unroll
    for (int i = 0; i < 14; ++i) p.Wp[i] = W_inproj[i];
#pragma unroll
    for (int k = 0; k < 4; ++k) {
        p.cw0[k] = conv_w[2 * k];
        p.cw1[k] = conv_w[2 * k + 1];
        p.cb[k]  = conv_b[k];
    }
    p.dtb = dt_bias[0];
    p.A   = -__expf(A_log[0]);
    return p;
}

// One timestep: from obs (o0,o1,o2) and previous pre-conv xBC (pp[4]),
// produce decay a, input b0/b1, and output-path values.
struct Step {
    float a, b0, b1;     // state update s = a*s + b
    float Cv, xh0, xh1;  // C and silu'd x (for y = C*s + D*x)
    float z0, z1;        // gate pre-activations
};

__device__ __forceinline__ Step do_step(const Pars& p, float o0, float o1, float o2,
                                        float pp[4]) {
    float x0 = fmaf(p.Wi[2], o2, fmaf(p.Wi[1], o1, fmaf(p.Wi[0], o0, p.bi[0])));
    float x1 = fmaf(p.Wi[5], o2, fmaf(p.Wi[4], o1, fmaf(p.Wi[3], o0, p.bi[1])));
    float z0 = fmaf(p.Wp[1], x1, p.Wp[0] * x0);
    float z1 = fmaf(p.Wp[3], x1, p.Wp[2] * x0);
    float q0 = fmaf(p.Wp[5], x1, p.Wp[4] * x0);
    float q1 = fmaf(p.Wp[7], x1, p.Wp[6] * x0);
    float q2 = fmaf(p.Wp[9], x1, p.Wp[8] * x0);
    float q3 = fmaf(p.Wp[11], x1, p.Wp[10] * x0);
    float dtr = fmaf(p.Wp[13], x1, fmaf(p.Wp[12], x0, p.dtb));
    float dt = softplus_f(dtr);
    // depthwise causal conv (k=2) + bias
    float c0 = fmaf(pp[0], p.cw0[0], fmaf(q0, p.cw1[0], p.cb[0]));
    float c1 = fmaf(pp[1], p.cw0[1], fmaf(q1, p.cw1[1], p.cb[1]));
    float c2 = fmaf(pp[2], p.cw0[2], fmaf(q2, p.cw1[2], p.cb[2]));
    float c3 = fmaf(pp[3], p.cw0[3], fmaf(q3, p.cw1[3], p.cb[3]));
    pp[0] = q0; pp[1] = q1; pp[2] = q2; pp[3] = q3;
    float xh0 = silu_f(c0);
    float xh1 = silu_f(c1);
    float Bv  = silu_f(c2);
    float Cv  = silu_f(c3);
    float a = __expf(p.A * dt);
    Step s;
    s.a = a;
    float xd0 = xh0 * dt, xd1 = xh1 * dt;
    s.b0 = Bv * xd0; s.b1 = Bv * xd1;
    s.Cv = Cv; s.xh0 = xh0; s.xh1 = xh1; s.z0 = z0; s.z1 = z1;
    return s;
}

// pre-conv xBC at t0-1 (zeros if t0==0, matching the reference's zero pad)
__device__ __forceinline__ void init_pp(const Pars& p, const float* __restrict__ obs,
                                        int t0, int b, float pp[4]) {
    if (t0 == 0) { pp[0] = pp[1] = pp[2] = pp[3] = 0.0f; return; }
    const float* op = obs + ((size_t)(t0 - 1) * BKB + b) * OBSD;
    float o0 = op[0], o1 = op[1], o2 = op[2];
    float x0 = fmaf(p.Wi[2], o2, fmaf(p.Wi[1], o1, fmaf(p.Wi[0], o0, p.bi[0])));
    float x1 = fmaf(p.Wi[5], o2, fmaf(p.Wi[4], o1, fmaf(p.Wi[3], o0, p.bi[1])));
    pp[0] = fmaf(p.Wp[5], x1, p.Wp[4] * x0);
    pp[1] = fmaf(p.Wp[7], x1, p.Wp[6] * x0);
    pp[2] = fmaf(p.Wp[9], x1, p.Wp[8] * x0);
    pp[3] = fmaf(p.Wp[11], x1, p.Wp[10] * x0);
}

// Kernel 1: per-(chunk, batch) affine summary of the state recurrence.
// ws layout: [0..NC*BK) = A_prod, [NC*BK..2*NC*BK) = B0, [2*NC*BK..3*NC*BK) = B1
__global__ __launch_bounds__(BKB) void k_summary(
    const float* __restrict__ obs, const float* __restrict__ W_in,
    const float* __restrict__ b_in, const float* __restrict__ W_inproj,
    const float* __restrict__ conv_w, const float* __restrict__ conv_b,
    const float* __restrict__ dt_bias, const float* __restrict__ A_log,
    float* __restrict__ ws) {
    int b = threadIdx.x;
    int c = blockIdx.x;
    int t0 = c * TC;
    Pars p = load_pars(W_in, b_in, W_inproj, conv_w, conv_b, dt_bias, A_log);
    float pp[4];
    init_pp(p, obs, t0, b, pp);
    float Aa = 1.0f, Ba0 = 0.0f, Ba1 = 0.0f;
#pragma unroll
    for (int i = 0; i < TC; ++i) {
        const float* op = obs + ((size_t)(t0 + i) * BKB + b) * OBSD;
        Step s = do_step(p, op[0], op[1], op[2], pp);
        Aa  *= s.a;
        Ba0 = fmaf(s.a, Ba0, s.b0);
        Ba1 = fmaf(s.a, Ba1, s.b1);
    }
    int idx = c * BKB + b;
    ws[idx]                 = Aa;
    ws[NCHUNK * BKB + idx]  = Ba0;
    ws[2 * NCHUNK * BKB + idx] = Ba1;
}

// Kernel 2: compose prior chunk summaries -> incoming state, then recompute
// the chunk's steps and write q and logits.
__global__ __launch_bounds__(BKB) void k_apply(
    const float* __restrict__ obs, const float* __restrict__ W_in,
    const float* __restrict__ b_in, const float* __restrict__ W_inproj,
    const float* __restrict__ conv_w, const float* __restrict__ conv_b,
    const float* __restrict__ dt_bias, const float* __restrict__ A_log,
    const float* __restrict__ Dp_, const float* __restrict__ norm_w,
    const float* __restrict__ W_out, const float* __restrict__ head,
    const float* __restrict__ log_tau, const float* __restrict__ ws,
    float* __restrict__ out) {
    int b = threadIdx.x;
    int c = blockIdx.x;
    int t0 = c * TC;
    Pars p = load_pars(W_in, b_in, W_inproj, conv_w, conv_b, dt_bias, A_log);
    float Dp = Dp_[0];
    // fold norm_w and the summed output projection into 2 coefficients
    float w0 = (W_out[0] + W_out[2]) * norm_w[0];
    float w1 = (W_out[1] + W_out[3]) * norm_w[1];
    float hscale = softplus_f(head[0]);
    float itau   = __expf(-log_tau[0]);

    // incoming state for this chunk: compose summaries of chunks [0, c)
    float s0 = 0.0f, s1 = 0.0f;
    for (int cc = 0; cc < c; ++cc) {
        int idx = cc * BKB + b;
        float Av = ws[idx];
        float B0 = ws[NCHUNK * BKB + idx];
        float B1 = ws[2 * NCHUNK * BKB + idx];
        s0 = fmaf(Av, s0, B0);
        s1 = fmaf(Av, s1, B1);
    }

    float pp[4];
    init_pp(p, obs, t0, b, pp);
#pragma unroll
    for (int i = 0; i < TC; ++i) {
        int t = t0 + i;
        const float* op = obs + ((size_t)t * BKB + b) * OBSD;
        Step s = do_step(p, op[0], op[1], op[2], pp);
        s0 = fmaf(s.a, s0, s.b0);
        s1 = fmaf(s.a, s1, s.b1);
        float y0 = fmaf(s.Cv, s0, s.xh0 * Dp);
        float y1 = fmaf(s.Cv, s1, s.xh1 * Dp);
        y0 *= silu_f(s.z0);
        y1 *= silu_f(s.z1);
        float ms = fmaf(0.5f, y0 * y0 + y1 * y1, 0.0f) ;
        float r  = __builtin_amdgcn_rsqf(0.5f * (y0 * y0 + y1 * y1) + EPSF);
        (void)ms;
        float q = (w0 * y0 + w1 * y1) * r * hscale;
        out[(size_t)t * BKB + b]       = q;
        out[TOT + (size_t)t * BKB + b] = q * itau;
    }
}

extern "C" void kernel_launch(void* const* d_in, const int* in_sizes, int n_in,
                              void* d_out, int out_size, void* d_ws, size_t ws_size,
                              hipStream_t stream) {
    const float* obs      = (const float*)d_in[0];
    const float* W_in     = (const float*)d_in[1];
    const float* b_in     = (const float*)d_in[2];
    const float* W_inproj = (const float*)d_in[3];
    const float* conv_w   = (const float*)d_in[4];
    const float* conv_b   = (const float*)d_in[5];
    const float* dt_bias  = (const float*)d_in[6];
    const float* A_log    = (const float*)d_in[7];
    const float* Dp       = (const float*)d_in[8];
    const float* norm_w   = (const float*)d_in[9];
    const float* W_out    = (const float*)d_in[10];
    const float* head     = (const float*)d_in[11];
    const float* log_tau  = (const float*)d_in[12];
    // d_in[13] = k (unused in compute)

    float* ws  = (float*)d_ws;   // needs 3 * NCHUNK * BKB * 4 = 768 KiB
    float* out = (float*)d_out;

    k_summary<<<NCHUNK, BKB, 0, stream>>>(obs, W_in, b_in, W_inproj, conv_w, conv_b,
                                          dt_bias, A_log, ws);
    k_apply<<<NCHUNK, BKB, 0, stream>>>(obs, W_in, b_in, W_inproj, conv_w, conv_b,
                                        dt_bias, A_log, Dp, norm_w, W_out, head,
                                        log_tau, ws, out);
}

// Round 2
// 26.808 us; speedup vs baseline: 3.0415x; 3.0415x over previous
//
#include <hip/hip_runtime.h>

// Problem constants (from reference)
#define T_LEN   4096
#define BKB     256            // B_ENV * K_OPT
#define OBSD    3
#define NCHUNK  512            // time chunks
#define TC      (T_LEN / NCHUNK)   // 8 steps per chunk
#define SCH     32             // chunks per super-chunk
#define NSUP    (NCHUNK / SCH) // 16 super-chunks
#define CH      (NCHUNK * BKB) // elements per level-0 summary array
#define SU      (NSUP * BKB)
#define TOT     (T_LEN * BKB)  // elements per output tensor
#define EPSF    1e-5f

// ws float layout:
//   [0, CH)        A_c      per-chunk decay product
//   [CH, 2CH)      B0_c     per-chunk affine offset, ch 0
//   [2CH, 3CH)     B1_c     per-chunk affine offset, ch 1
//   [3CH, 3CH+SU)        A_s   per-super summaries
//   [3CH+SU, 3CH+2SU)    B0_s
//   [3CH+2SU, 3CH+3SU)   B1_s
// total = 3*CH + 3*SU = 405504 floats = 1.62 MB

// ---- fast math helpers ----
__device__ __forceinline__ float sigmoid_f(float x) {
    return __builtin_amdgcn_rcpf(1.0f + __expf(-x));
}
__device__ __forceinline__ float silu_f(float x) { return x * sigmoid_f(x); }
__device__ __forceinline__ float softplus_f(float x) {
    return x > 15.0f ? x : __logf(1.0f + __expf(x));
}

// ---- per-thread parameter block (all uniform; compiler scalarizes) ----
struct Pars {
    float Wi[6];    // W_in (2,3) row-major
    float bi[2];
    float Wp[14];   // W_inproj (7,2) row-major
    float cw0[4], cw1[4], cb[4];   // conv_w (4,2), conv_b
    float dtb;      // dt_bias[0]
    float A;        // -exp(A_log[0])
};

__device__ __forceinline__ Pars load_pars(const float* W_in, const float* b_in,
                                          const float* W_inproj, const float* conv_w,
                                          const float* conv_b, const float* dt_bias,
                                          const float* A_log) {
    Pars p;
#pragma unroll
    for (int i = 0; i < 6; ++i) p.Wi[i] = W_in[i];
    p.bi[0] = b_in[0]; p.bi[1] = b_in[1];
#pragma unroll
    for (int i = 0; i < 14; ++i) p.Wp[i] = W_inproj[i];
#pragma unroll
    for (int k = 0; k < 4; ++k) {
        p.cw0[k] = conv_w[2 * k];
        p.cw1[k] = conv_w[2 * k + 1];
        p.cb[k]  = conv_b[k];
    }
    p.dtb = dt_bias[0];
    p.A   = -__expf(A_log[0]);
    return p;
}

struct Step {
    float a, b0, b1;     // state update s = a*s + b
    float Cv, xh0, xh1;  // C and silu'd x (for y = C*s + D*x)
    float z0, z1;        // gate pre-activations
};

__device__ __forceinline__ Step do_step(const Pars& p, float o0, float o1, float o2,
                                        float pp[4]) {
    float x0 = fmaf(p.Wi[2], o2, fmaf(p.Wi[1], o1, fmaf(p.Wi[0], o0, p.bi[0])));
    float x1 = fmaf(p.Wi[5], o2, fmaf(p.Wi[4], o1, fmaf(p.Wi[3], o0, p.bi[1])));
    float z0 = fmaf(p.Wp[1], x1, p.Wp[0] * x0);
    float z1 = fmaf(p.Wp[3], x1, p.Wp[2] * x0);
    float q0 = fmaf(p.Wp[5], x1, p.Wp[4] * x0);
    float q1 = fmaf(p.Wp[7], x1, p.Wp[6] * x0);
    float q2 = fmaf(p.Wp[9], x1, p.Wp[8] * x0);
    float q3 = fmaf(p.Wp[11], x1, p.Wp[10] * x0);
    float dtr = fmaf(p.Wp[13], x1, fmaf(p.Wp[12], x0, p.dtb));
    float dt = softplus_f(dtr);
    float c0 = fmaf(pp[0], p.cw0[0], fmaf(q0, p.cw1[0], p.cb[0]));
    float c1 = fmaf(pp[1], p.cw0[1], fmaf(q1, p.cw1[1], p.cb[1]));
    float c2 = fmaf(pp[2], p.cw0[2], fmaf(q2, p.cw1[2], p.cb[2]));
    float c3 = fmaf(pp[3], p.cw0[3], fmaf(q3, p.cw1[3], p.cb[3]));
    pp[0] = q0; pp[1] = q1; pp[2] = q2; pp[3] = q3;
    float xh0 = silu_f(c0);
    float xh1 = silu_f(c1);
    float Bv  = silu_f(c2);
    float Cv  = silu_f(c3);
    float a = __expf(p.A * dt);
    Step s;
    s.a = a;
    float xd0 = xh0 * dt, xd1 = xh1 * dt;
    s.b0 = Bv * xd0; s.b1 = Bv * xd1;
    s.Cv = Cv; s.xh0 = xh0; s.xh1 = xh1; s.z0 = z0; s.z1 = z1;
    return s;
}

// pre-conv xBC at t0-1 (zeros if t0==0, matching the reference's zero pad)
__device__ __forceinline__ void init_pp(const Pars& p, const float* __restrict__ obs,
                                        int t0, int b, float pp[4]) {
    if (t0 == 0) { pp[0] = pp[1] = pp[2] = pp[3] = 0.0f; return; }
    const float* op = obs + ((size_t)(t0 - 1) * BKB + b) * OBSD;
    float o0 = op[0], o1 = op[1], o2 = op[2];
    float x0 = fmaf(p.Wi[2], o2, fmaf(p.Wi[1], o1, fmaf(p.Wi[0], o0, p.bi[0])));
    float x1 = fmaf(p.Wi[5], o2, fmaf(p.Wi[4], o1, fmaf(p.Wi[3], o0, p.bi[1])));
    pp[0] = fmaf(p.Wp[5], x1, p.Wp[4] * x0);
    pp[1] = fmaf(p.Wp[7], x1, p.Wp[6] * x0);
    pp[2] = fmaf(p.Wp[9], x1, p.Wp[8] * x0);
    pp[3] = fmaf(p.Wp[11], x1, p.Wp[10] * x0);
}

// Kernel 1: per-(chunk, batch) affine summary of the state recurrence.
__global__ __launch_bounds__(BKB) void k_summary(
    const float* __restrict__ obs, const float* __restrict__ W_in,
    const float* __restrict__ b_in, const float* __restrict__ W_inproj,
    const float* __restrict__ conv_w, const float* __restrict__ conv_b,
    const float* __restrict__ dt_bias, const float* __restrict__ A_log,
    float* __restrict__ ws) {
    int b = threadIdx.x;
    int c = blockIdx.x;
    int t0 = c * TC;
    Pars p = load_pars(W_in, b_in, W_inproj, conv_w, conv_b, dt_bias, A_log);
    float pp[4];
    init_pp(p, obs, t0, b, pp);
    float Aa = 1.0f, Ba0 = 0.0f, Ba1 = 0.0f;
#pragma unroll
    for (int i = 0; i < TC; ++i) {
        const float* op = obs + ((size_t)(t0 + i) * BKB + b) * OBSD;
        Step s = do_step(p, op[0], op[1], op[2], pp);
        Aa  *= s.a;
        Ba0 = fmaf(s.a, Ba0, s.b0);
        Ba1 = fmaf(s.a, Ba1, s.b1);
    }
    int idx = c * BKB + b;
    ws[idx]          = Aa;
    ws[CH + idx]     = Ba0;
    ws[2 * CH + idx] = Ba1;
}

// Kernel 2: per-super-chunk summary = composition of its SCH chunk summaries.
__global__ __launch_bounds__(BKB) void k_super(float* __restrict__ ws) {
    int b = threadIdx.x;
    int s = blockIdx.x;
    float Aa = 1.0f, B0 = 0.0f, B1 = 0.0f;
    int c0 = s * SCH;
#pragma unroll 4
    for (int i = 0; i < SCH; ++i) {
        int idx = (c0 + i) * BKB + b;
        float Av = ws[idx];
        float b0 = ws[CH + idx];
        float b1 = ws[2 * CH + idx];
        Aa *= Av;
        B0 = fmaf(Av, B0, b0);
        B1 = fmaf(Av, B1, b1);
    }
    int sidx = s * BKB + b;
    ws[3 * CH + sidx]          = Aa;
    ws[3 * CH + SU + sidx]     = B0;
    ws[3 * CH + 2 * SU + sidx] = B1;
}

// Kernel 3: incoming state = compose(super summaries [0,S)) then
// compose(chunk summaries [S*SCH, c)); recompute the chunk, write q & logits.
__global__ __launch_bounds__(BKB) void k_apply(
    const float* __restrict__ obs, const float* __restrict__ W_in,
    const float* __restrict__ b_in, const float* __restrict__ W_inproj,
    const float* __restrict__ conv_w, const float* __restrict__ conv_b,
    const float* __restrict__ dt_bias, const float* __restrict__ A_log,
    const float* __restrict__ Dp_, const float* __restrict__ norm_w,
    const float* __restrict__ W_out, const float* __restrict__ head,
    const float* __restrict__ log_tau, const float* __restrict__ ws,
    float* __restrict__ out) {
    int b = threadIdx.x;
    int c = blockIdx.x;
    int S = c / SCH;
    int t0 = c * TC;
    Pars p = load_pars(W_in, b_in, W_inproj, conv_w, conv_b, dt_bias, A_log);
    float Dp = Dp_[0];
    float w0 = (W_out[0] + W_out[2]) * norm_w[0];
    float w1 = (W_out[1] + W_out[3]) * norm_w[1];
    float hscale = softplus_f(head[0]);
    float itau   = __expf(-log_tau[0]);

    // state after all complete super-chunks [0, S)
    float s0 = 0.0f, s1 = 0.0f;
#pragma unroll 4
    for (int ss = 0; ss < S; ++ss) {
        int sidx = ss * BKB + b;
        float Av = ws[3 * CH + sidx];
        float B0 = ws[3 * CH + SU + sidx];
        float B1 = ws[3 * CH + 2 * SU + sidx];
        s0 = fmaf(Av, s0, B0);
        s1 = fmaf(Av, s1, B1);
    }
    // then chunks [S*SCH, c)
#pragma unroll 4
    for (int cc = S * SCH; cc < c; ++cc) {
        int idx = cc * BKB + b;
        float Av = ws[idx];
        float B0 = ws[CH + idx];
        float B1 = ws[2 * CH + idx];
        s0 = fmaf(Av, s0, B0);
        s1 = fmaf(Av, s1, B1);
    }

    float pp[4];
    init_pp(p, obs, t0, b, pp);
#pragma unroll
    for (int i = 0; i < TC; ++i) {
        int t = t0 + i;
        const float* op = obs + ((size_t)t * BKB + b) * OBSD;
        Step s = do_step(p, op[0], op[1], op[2], pp);
        s0 = fmaf(s.a, s0, s.b0);
        s1 = fmaf(s.a, s1, s.b1);
        float y0 = fmaf(s.Cv, s0, s.xh0 * Dp);
        float y1 = fmaf(s.Cv, s1, s.xh1 * Dp);
        y0 *= silu_f(s.z0);
        y1 *= silu_f(s.z1);
        float r  = __builtin_amdgcn_rsqf(0.5f * (y0 * y0 + y1 * y1) + EPSF);
        float q = (w0 * y0 + w1 * y1) * r * hscale;
        out[(size_t)t * BKB + b]       = q;
        out[TOT + (size_t)t * BKB + b] = q * itau;
    }
}

extern "C" void kernel_launch(void* const* d_in, const int* in_sizes, int n_in,
                              void* d_out, int out_size, void* d_ws, size_t ws_size,
                              hipStream_t stream) {
    const float* obs      = (const float*)d_in[0];
    const float* W_in     = (const float*)d_in[1];
    const float* b_in     = (const float*)d_in[2];
    const float* W_inproj = (const float*)d_in[3];
    const float* conv_w   = (const float*)d_in[4];
    const float* conv_b   = (const float*)d_in[5];
    const float* dt_bias  = (const float*)d_in[6];
    const float* A_log    = (const float*)d_in[7];
    const float* Dp       = (const float*)d_in[8];
    const float* norm_w   = (const float*)d_in[9];
    const float* W_out    = (const float*)d_in[10];
    const float* head     = (const float*)d_in[11];
    const float* log_tau  = (const float*)d_in[12];
    // d_in[13] = k (unused in compute)

    float* ws  = (float*)d_ws;   // needs (3*CH + 3*SU)*4 = 1.62 MB
    float* out = (float*)d_out;

    k_summary<<<NCHUNK, BKB, 0, stream>>>(obs, W_in, b_in, W_inproj, conv_w, conv_b,
                                          dt_bias, A_log, ws);
    k_super<<<NSUP, BKB, 0, stream>>>(ws);
    k_apply<<<NCHUNK, BKB, 0, stream>>>(obs, W_in, b_in, W_inproj, conv_w, conv_b,
                                        dt_bias, A_log, Dp, norm_w, W_out, head,
                                        log_tau, ws, out);
}

// Round 3
// 25.104 us; speedup vs baseline: 3.2481x; 1.0679x over previous
//
#include <hip/hip_runtime.h>

// Problem constants (from reference)
#define T_LEN   4096
#define BKB     256            // B_ENV * K_OPT
#define OBSD    3
#define NCHUNK  512            // time chunks
#define TC      (T_LEN / NCHUNK)   // 8 steps per chunk
#define CH      (NCHUNK * BKB) // elements per level-0 summary array
#define TOT     (T_LEN * BKB)  // elements per output tensor
#define EPSF    1e-5f

// ws float layout (total 5*CH*4B = 2.62 MB):
//   [0, CH)      A_c    per-chunk decay product
//   [CH, 2CH)    B0_c   per-chunk affine offset, ch 0
//   [2CH, 3CH)   B1_c   per-chunk affine offset, ch 1
//   [3CH, 4CH)   s0_in  incoming state ch 0 for each chunk (exclusive prefix)
//   [4CH, 5CH)   s1_in  incoming state ch 1

// ---- fast math helpers ----
__device__ __forceinline__ float sigmoid_f(float x) {
    return __builtin_amdgcn_rcpf(1.0f + __expf(-x));
}
__device__ __forceinline__ float silu_f(float x) { return x * sigmoid_f(x); }
__device__ __forceinline__ float softplus_f(float x) {
    return x > 15.0f ? x : __logf(1.0f + __expf(x));
}

// ---- per-thread parameter block (all uniform; compiler scalarizes) ----
struct Pars {
    float Wi[6];    // W_in (2,3) row-major
    float bi[2];
    float Wp[14];   // W_inproj (7,2) row-major
    float cw0[4], cw1[4], cb[4];   // conv_w (4,2), conv_b
    float dtb;      // dt_bias[0]
    float A;        // -exp(A_log[0])
};

__device__ __forceinline__ Pars load_pars(const float* W_in, const float* b_in,
                                          const float* W_inproj, const float* conv_w,
                                          const float* conv_b, const float* dt_bias,
                                          const float* A_log) {
    Pars p;
#pragma unroll
    for (int i = 0; i < 6; ++i) p.Wi[i] = W_in[i];
    p.bi[0] = b_in[0]; p.bi[1] = b_in[1];
#pragma unroll
    for (int i = 0; i < 14; ++i) p.Wp[i] = W_inproj[i];
#pragma unroll
    for (int k = 0; k < 4; ++k) {
        p.cw0[k] = conv_w[2 * k];
        p.cw1[k] = conv_w[2 * k + 1];
        p.cb[k]  = conv_b[k];
    }
    p.dtb = dt_bias[0];
    p.A   = -__expf(A_log[0]);
    return p;
}

struct Step {
    float a, b0, b1;     // state update s = a*s + b
    float Cv, xh0, xh1;  // C and silu'd x (for y = C*s + D*x)
    float z0, z1;        // gate pre-activations
};

__device__ __forceinline__ Step do_step(const Pars& p, float o0, float o1, float o2,
                                        float pp[4]) {
    float x0 = fmaf(p.Wi[2], o2, fmaf(p.Wi[1], o1, fmaf(p.Wi[0], o0, p.bi[0])));
    float x1 = fmaf(p.Wi[5], o2, fmaf(p.Wi[4], o1, fmaf(p.Wi[3], o0, p.bi[1])));
    float z0 = fmaf(p.Wp[1], x1, p.Wp[0] * x0);
    float z1 = fmaf(p.Wp[3], x1, p.Wp[2] * x0);
    float q0 = fmaf(p.Wp[5], x1, p.Wp[4] * x0);
    float q1 = fmaf(p.Wp[7], x1, p.Wp[6] * x0);
    float q2 = fmaf(p.Wp[9], x1, p.Wp[8] * x0);
    float q3 = fmaf(p.Wp[11], x1, p.Wp[10] * x0);
    float dtr = fmaf(p.Wp[13], x1, fmaf(p.Wp[12], x0, p.dtb));
    float dt = softplus_f(dtr);
    float c0 = fmaf(pp[0], p.cw0[0], fmaf(q0, p.cw1[0], p.cb[0]));
    float c1 = fmaf(pp[1], p.cw0[1], fmaf(q1, p.cw1[1], p.cb[1]));
    float c2 = fmaf(pp[2], p.cw0[2], fmaf(q2, p.cw1[2], p.cb[2]));
    float c3 = fmaf(pp[3], p.cw0[3], fmaf(q3, p.cw1[3], p.cb[3]));
    pp[0] = q0; pp[1] = q1; pp[2] = q2; pp[3] = q3;
    float xh0 = silu_f(c0);
    float xh1 = silu_f(c1);
    float Bv  = silu_f(c2);
    float Cv  = silu_f(c3);
    float a = __expf(p.A * dt);
    Step s;
    s.a = a;
    float xd0 = xh0 * dt, xd1 = xh1 * dt;
    s.b0 = Bv * xd0; s.b1 = Bv * xd1;
    s.Cv = Cv; s.xh0 = xh0; s.xh1 = xh1; s.z0 = z0; s.z1 = z1;
    return s;
}

// pre-conv xBC at t0-1 (zeros if t0==0, matching the reference's zero pad)
__device__ __forceinline__ void init_pp(const Pars& p, const float* __restrict__ obs,
                                        int t0, int b, float pp[4]) {
    if (t0 == 0) { pp[0] = pp[1] = pp[2] = pp[3] = 0.0f; return; }
    const float* op = obs + ((size_t)(t0 - 1) * BKB + b) * OBSD;
    float o0 = op[0], o1 = op[1], o2 = op[2];
    float x0 = fmaf(p.Wi[2], o2, fmaf(p.Wi[1], o1, fmaf(p.Wi[0], o0, p.bi[0])));
    float x1 = fmaf(p.Wi[5], o2, fmaf(p.Wi[4], o1, fmaf(p.Wi[3], o0, p.bi[1])));
    pp[0] = fmaf(p.Wp[5], x1, p.Wp[4] * x0);
    pp[1] = fmaf(p.Wp[7], x1, p.Wp[6] * x0);
    pp[2] = fmaf(p.Wp[9], x1, p.Wp[8] * x0);
    pp[3] = fmaf(p.Wp[11], x1, p.Wp[10] * x0);
}

// Kernel 1: per-(chunk, batch) affine summary of the state recurrence.
__global__ __launch_bounds__(BKB) void k_summary(
    const float* __restrict__ obs, const float* __restrict__ W_in,
    const float* __restrict__ b_in, const float* __restrict__ W_inproj,
    const float* __restrict__ conv_w, const float* __restrict__ conv_b,
    const float* __restrict__ dt_bias, const float* __restrict__ A_log,
    float* __restrict__ ws) {
    int b = threadIdx.x;
    int c = blockIdx.x;
    int t0 = c * TC;
    Pars p = load_pars(W_in, b_in, W_inproj, conv_w, conv_b, dt_bias, A_log);
    float pp[4];
    init_pp(p, obs, t0, b, pp);
    float Aa = 1.0f, Ba0 = 0.0f, Ba1 = 0.0f;
#pragma unroll
    for (int i = 0; i < TC; ++i) {
        const float* op = obs + ((size_t)(t0 + i) * BKB + b) * OBSD;
        Step s = do_step(p, op[0], op[1], op[2], pp);
        Aa  *= s.a;
        Ba0 = fmaf(s.a, Ba0, s.b0);
        Ba1 = fmaf(s.a, Ba1, s.b1);
    }
    int idx = c * BKB + b;
    ws[idx]          = Aa;
    ws[CH + idx]     = Ba0;
    ws[2 * CH + idx] = Ba1;
}

// Kernel 2: Hillis-Steele scan of the affine chunk maps along the chunk axis,
// one block per batch lane. Writes the EXCLUSIVE prefix applied to s=0, i.e.
// each chunk's incoming state (= B-component of inclusive prefix of previous).
__global__ __launch_bounds__(NCHUNK) void k_scan(float* __restrict__ ws) {
    __shared__ float sA[NCHUNK], sB0[NCHUNK], sB1[NCHUNK];
    int b = blockIdx.x;
    int i = threadIdx.x;
    int idx = i * BKB + b;
    float A  = ws[idx];
    float B0 = ws[CH + idx];
    float B1 = ws[2 * CH + idx];
    sA[i] = A; sB0[i] = B0; sB1[i] = B1;
    __syncthreads();
#pragma unroll
    for (int off = 1; off < NCHUNK; off <<= 1) {
        float pA = 1.0f, pB0 = 0.0f, pB1 = 0.0f;
        if (i >= off) { pA = sA[i - off]; pB0 = sB0[i - off]; pB1 = sB1[i - off]; }
        __syncthreads();
        // compose: cur ∘ prev  (prev applied first)
        B0 = fmaf(A, pB0, B0);
        B1 = fmaf(A, pB1, B1);
        A  = A * pA;
        sA[i] = A; sB0[i] = B0; sB1[i] = B1;
        __syncthreads();
    }
    // incoming state of chunk i+1 is inclusive[i] applied to 0 = (B0, B1)
    if (i < NCHUNK - 1) {
        ws[3 * CH + (i + 1) * BKB + b] = B0;
        ws[4 * CH + (i + 1) * BKB + b] = B1;
    }
    if (i == 0) {
        ws[3 * CH + b] = 0.0f;
        ws[4 * CH + b] = 0.0f;
    }
}

// Kernel 3: read incoming state, recompute the chunk's steps, write q & logits.
__global__ __launch_bounds__(BKB) void k_apply(
    const float* __restrict__ obs, const float* __restrict__ W_in,
    const float* __restrict__ b_in, const float* __restrict__ W_inproj,
    const float* __restrict__ conv_w, const float* __restrict__ conv_b,
    const float* __restrict__ dt_bias, const float* __restrict__ A_log,
    const float* __restrict__ Dp_, const float* __restrict__ norm_w,
    const float* __restrict__ W_out, const float* __restrict__ head,
    const float* __restrict__ log_tau, const float* __restrict__ ws,
    float* __restrict__ out) {
    int b = threadIdx.x;
    int c = blockIdx.x;
    int t0 = c * TC;
    Pars p = load_pars(W_in, b_in, W_inproj, conv_w, conv_b, dt_bias, A_log);
    float Dp = Dp_[0];
    float w0 = (W_out[0] + W_out[2]) * norm_w[0];
    float w1 = (W_out[1] + W_out[3]) * norm_w[1];
    float hscale = softplus_f(head[0]);
    float itau   = __expf(-log_tau[0]);

    float s0 = ws[3 * CH + c * BKB + b];
    float s1 = ws[4 * CH + c * BKB + b];

    float pp[4];
    init_pp(p, obs, t0, b, pp);
#pragma unroll
    for (int i = 0; i < TC; ++i) {
        int t = t0 + i;
        const float* op = obs + ((size_t)t * BKB + b) * OBSD;
        Step s = do_step(p, op[0], op[1], op[2], pp);
        s0 = fmaf(s.a, s0, s.b0);
        s1 = fmaf(s.a, s1, s.b1);
        float y0 = fmaf(s.Cv, s0, s.xh0 * Dp);
        float y1 = fmaf(s.Cv, s1, s.xh1 * Dp);
        y0 *= silu_f(s.z0);
        y1 *= silu_f(s.z1);
        float r  = __builtin_amdgcn_rsqf(0.5f * (y0 * y0 + y1 * y1) + EPSF);
        float q = (w0 * y0 + w1 * y1) * r * hscale;
        out[(size_t)t * BKB + b]       = q;
        out[TOT + (size_t)t * BKB + b] = q * itau;
    }
}

extern "C" void kernel_launch(void* const* d_in, const int* in_sizes, int n_in,
                              void* d_out, int out_size, void* d_ws, size_t ws_size,
                              hipStream_t stream) {
    const float* obs      = (const float*)d_in[0];
    const float* W_in     = (const float*)d_in[1];
    const float* b_in     = (const float*)d_in[2];
    const float* W_inproj = (const float*)d_in[3];
    const float* conv_w   = (const float*)d_in[4];
    const float* conv_b   = (const float*)d_in[5];
    const float* dt_bias  = (const float*)d_in[6];
    const float* A_log    = (const float*)d_in[7];
    const float* Dp       = (const float*)d_in[8];
    const float* norm_w   = (const float*)d_in[9];
    const float* W_out    = (const float*)d_in[10];
    const float* head     = (const float*)d_in[11];
    const float* log_tau  = (const float*)d_in[12];
    // d_in[13] = k (unused in compute)

    float* ws  = (float*)d_ws;   // needs 5*CH*4 = 2.62 MB
    float* out = (float*)d_out;

    k_summary<<<NCHUNK, BKB, 0, stream>>>(obs, W_in, b_in, W_inproj, conv_w, conv_b,
                                          dt_bias, A_log, ws);
    k_scan<<<BKB, NCHUNK, 0, stream>>>(ws);
    k_apply<<<NCHUNK, BKB, 0, stream>>>(obs, W_in, b_in, W_inproj, conv_w, conv_b,
                                        dt_bias, A_log, Dp, norm_w, W_out, head,
                                        log_tau, ws, out);
}